// Round 6
// baseline (138.867 us; speedup 1.0000x reference)
//
#include <hip/hip_runtime.h>

#define AN 256
#define BN 64
#define DN 768
#define LN 2
#define G1N 4
#define G2N 8
#define KI (DN / 32)   // 24 k-iterations of 32
#define PAD 776        // 768 + 8 bf16 pad -> 1552B row stride (2-way bank alias = free)
#define MAGIC 0x5F3C9A71   // non-byte-repeating: memset-style poison cannot forge it

typedef __attribute__((ext_vector_type(8))) short short8;   // 8 bf16
typedef __attribute__((ext_vector_type(4))) short bf16x4;   // 4 bf16
typedef __attribute__((ext_vector_type(4))) float floatx4;  // MFMA acc

static __device__ __forceinline__ unsigned short f2bf(float f) {
    union { float f; unsigned int u; } v; v.f = f;
    unsigned int r = v.u + 0x7FFF + ((v.u >> 16) & 1);  // RNE
    return (unsigned short)(r >> 16);
}
static __device__ __forceinline__ unsigned int pack2(float a, float b) {
    return (unsigned int)f2bf(a) | ((unsigned int)f2bf(b) << 16);
}
static __device__ __forceinline__ void sig_flag(int* f) {
    __hip_atomic_store(f, MAGIC, __ATOMIC_RELAXED, __HIP_MEMORY_SCOPE_AGENT);
}
static __device__ __forceinline__ void wait_flag(int* f) {
    while (__hip_atomic_load(f, __ATOMIC_RELAXED, __HIP_MEMORY_SCOPE_AGENT) != MAGIC)
        __builtin_amdgcn_s_sleep(2);
}

// ---------------------------------------------------------------------------
// k_all: ONE regular launch, grid 256 x 256. 99 KB static LDS -> exactly
// 1 block/CU -> with grid == #CU (256) ALL blocks are resident from dispatch,
// so the flag pipeline below cannot deadlock: producers never wait; consumers
// wait only on resident producers.
//   bx <  48 : h1 producer (verbatim R5 body)  -> flags[bx]
//   48..143  : Wc producer (verbatim R5 body)  -> flags[bx]
//   144..151 : bc producer (verbatim R5 body)  -> flags[bx]
//   152..255 : out consumer: wait {h1[g] x12, all Wc, all bc} -> k_out body.
//              Block c handles job c-152, plus job c-152+104 if < 128
//              (the doubled jobs are group-3 high tiles, almost always empty).
// ---------------------------------------------------------------------------
__global__ __launch_bounds__(256) void k_all(
    const float* __restrict__ pooled, const float* __restrict__ W1,
    const float* __restrict__ b1, const float* __restrict__ W2,
    const float* __restrict__ b2, const float* __restrict__ Wh,
    const float* __restrict__ bh, const int* __restrict__ g1i,
    const int* __restrict__ g2i,
    unsigned short* __restrict__ h1, unsigned short* __restrict__ Wcs,
    float* __restrict__ bc, int* __restrict__ flags,
    float* __restrict__ out)
{
    __shared__ __align__(16) unsigned char smem[64 * PAD * 2];   // 99328 B, role-unioned
    const int tid = threadIdx.x, bx = blockIdx.x;
    const int lane = tid & 63, wave = tid >> 6;
    const int nn = lane & 15, quad = lane >> 4;

    if (bx < 48) {
        // ---------------- h1 producer ----------------
        unsigned short* ps = (unsigned short*)smem;              // [64][PAD] bf16
        {
            const float4* p4 = (const float4*)pooled;            // 12288 float4
            #pragma unroll
            for (int i = 0; i < 48; ++i) {
                const int idx = i * 256 + tid;
                float4 v = p4[idx];
                const int row = idx / 192, c4 = idx % 192;
                const unsigned long long w =
                    (unsigned long long)pack2(v.x, v.y) |
                    ((unsigned long long)pack2(v.z, v.w) << 32);
                *(unsigned long long*)(ps + row * PAD + c4 * 4) = w;
            }
        }
        __syncthreads();

        const int g = bx / 12, e0 = (bx % 12) * 64;
        const int e = e0 + wave * 16 + nn;
        const float* Wcol = W1 + (size_t)g * DN * DN + e;        // column e, stride DN
        const unsigned short* Ap = ps + nn * PAD + quad * 8;
        floatx4 acc[4] = {{0,0,0,0},{0,0,0,0},{0,0,0,0},{0,0,0,0}};
        #pragma unroll
        for (int kk = 0; kk < KI; ++kk) {
            const float* wk = Wcol + (size_t)(kk * 32 + quad * 8) * DN;
            short8 bf;
            #pragma unroll
            for (int j = 0; j < 8; ++j)
                bf[j] = (short)f2bf(wk[(size_t)j * DN]);
            #pragma unroll
            for (int mt = 0; mt < 4; ++mt) {
                short8 af = *(const short8*)(Ap + (mt * 16) * PAD + kk * 32);
                acc[mt] = __builtin_amdgcn_mfma_f32_16x16x32_bf16(af, bf, acc[mt], 0, 0, 0);
            }
        }
        const float bv = b1[g * DN + e];
        #pragma unroll
        for (int mt = 0; mt < 4; ++mt)
            #pragma unroll
            for (int r = 0; r < 4; ++r)
                h1[(size_t)g * BN * DN + (size_t)(mt * 16 + quad * 4 + r) * DN + e] =
                    f2bf(acc[mt][r] + bv);

        __syncthreads();
        if (tid == 0) { __threadfence(); sig_flag(&flags[bx]); }
    } else if (bx < 144) {
        // ---------------- Wc producer ----------------
        int* g2s  = (int*)smem;                                  // [256]
        int* lst2 = (int*)(smem + 1024);                         // [256]
        unsigned short* Whs = (unsigned short*)(smem + 2048);    // [16][PAD] bf16

        const int j = bx - 48, g = j / 12, mbase = (j % 12) * 64;

        // A = W2 rows -> regs (issue the big loads first; scan overlaps latency)
        const int m_row = mbase + wave * 16 + nn;
        const float* ap = W2 + ((size_t)g * DN + m_row) * DN + quad * 8;
        short8 Areg[KI];
        #pragma unroll
        for (int kk = 0; kk < KI; ++kk) {
            float4 a0 = *(const float4*)(ap + kk * 32);
            float4 a1 = *(const float4*)(ap + kk * 32 + 4);
            short8 af;
            af[0] = (short)f2bf(a0.x); af[1] = (short)f2bf(a0.y);
            af[2] = (short)f2bf(a0.z); af[3] = (short)f2bf(a0.w);
            af[4] = (short)f2bf(a1.x); af[5] = (short)f2bf(a1.y);
            af[6] = (short)f2bf(a1.z); af[7] = (short)f2bf(a1.w);
            Areg[kk] = af;
        }

        // in-block index scan: deterministic rank within g2 group
        g2s[tid] = g2i[tid];
        __syncthreads();
        const int my = g2s[tid];
        int rk = 0;
        for (int a2 = 0; a2 < tid; ++a2) rk += (g2s[a2] == my);
        if (my == g) lst2[rk] = tid;
        int n2g = 0;
        for (int a2 = 0; a2 < AN; ++a2) n2g += (g2s[a2] == g);
        __syncthreads();
        const int cols = 2 * n2g;

        const int al = tid >> 5, t32 = tid & 31;
        for (int c0 = 0; c0 < cols; c0 += 16) {
            // stage 8 annotators' Wh columns -> Whs[16][PAD] (l-de-interleaved)
            const int sidx = (c0 >> 1) + al;
            if (sidx < n2g) {
                const int a = lst2[sidx];
                const float4* wa4 = (const float4*)(Wh + (size_t)a * (DN * LN));
                #pragma unroll
                for (int i = 0; i < 12; ++i) {
                    const int f4 = i * 32 + t32;          // 0..383
                    float4 v = wa4[f4];
                    const int e2 = f4 * 2;                // elems e2, e2+1
                    *(unsigned int*)(Whs + (2 * al)     * PAD + e2) = pack2(v.x, v.z);
                    *(unsigned int*)(Whs + (2 * al + 1) * PAD + e2) = pack2(v.y, v.w);
                }
            }
            __syncthreads();
            const unsigned short* Brow = Whs + nn * PAD + quad * 8;
            floatx4 acc = {0, 0, 0, 0};
            #pragma unroll
            for (int kk = 0; kk < KI; ++kk) {
                short8 bf = *(const short8*)(Brow + kk * 32);
                acc = __builtin_amdgcn_mfma_f32_16x16x32_bf16(Areg[kk], bf, acc, 0, 0, 0);
            }
            const int c = c0 + nn;
            if (c < cols) {
                const int dbase = mbase + wave * 16 + quad * 4;
                bf16x4 v;
                #pragma unroll
                for (int r = 0; r < 4; ++r) v[r] = (short)f2bf(acc[r]);
                *(bf16x4*)(Wcs + (size_t)(g * 256 + c) * DN + dbase) = v;
            }
            __syncthreads();   // reads done before next tile's staging
        }

        __syncthreads();
        if (tid == 0) { __threadfence(); sig_flag(&flags[bx]); }
    } else if (bx < 152) {
        // ---------------- bc producer ----------------
        const int jb = bx - 144;
        const int aa = tid >> 3, jj = tid & 7;
        const int a = jb * 32 + aa;
        const int gv2 = g2i[a];
        const float* whp = Wh + (size_t)a * (DN * LN);
        const float* b2p = b2 + gv2 * DN;
        float acc0 = 0.f, acc1 = 0.f;
        #pragma unroll 4
        for (int i = 0; i < 48; ++i) {
            int e = jj * 96 + i * 2;
            float4 w4 = *(const float4*)(whp + e * 2);
            float2 bv = *(const float2*)(b2p + e);
            acc0 += bv.x * w4.x + bv.y * w4.z;
            acc1 += bv.x * w4.y + bv.y * w4.w;
        }
        #pragma unroll
        for (int off = 4; off; off >>= 1) {
            acc0 += __shfl_down(acc0, off, 64);
            acc1 += __shfl_down(acc1, off, 64);
        }
        if (jj == 0) {
            bc[a * 2 + 0] = acc0 + bh[a * 2 + 0];
            bc[a * 2 + 1] = acc1 + bh[a * 2 + 1];
        }
        __syncthreads();
        if (tid == 0) { __threadfence(); sig_flag(&flags[bx]); }
    } else {
        // ---------------- out consumer ----------------
        int* g1s  = (int*)smem;
        int* g2s  = (int*)(smem + 1024);
        int* lst1 = (int*)(smem + 2048);
        int* sx2  = (int*)(smem + 3072);

        const int j0 = bx - 152;
        const int njobs = (j0 < 24) ? 2 : 1;
        for (int ji = 0; ji < njobs; ++ji) {
            const int job = j0 + ji * 104;
            const int g = job >> 5;

            // acquire: distributed waits on {all Wc, all bc, h1[g] x12}
            if (tid < 96)       wait_flag(&flags[48 + tid]);
            else if (tid < 104) wait_flag(&flags[144 + (tid - 96)]);
            else if (tid < 116) wait_flag(&flags[g * 12 + (tid - 104)]);
            __syncthreads();
            __threadfence();

            // in-block index scan (deterministic; matches producers' layout)
            g1s[tid] = g1i[tid];
            g2s[tid] = g2i[tid];
            __syncthreads();
            const int m1 = g1s[tid], m2 = g2s[tid];
            int r1 = 0, r2 = 0;
            for (int a2 = 0; a2 < tid; ++a2) {
                r1 += (g1s[a2] == m1);
                r2 += (g2s[a2] == m2);
            }
            sx2[tid] = r2;
            if (m1 == g) lst1[r1] = tid;
            int n1g = 0;
            for (int a2 = 0; a2 < AN; ++a2) n1g += (g1s[a2] == g);
            __syncthreads();

            const int cols = 2 * n1g;
            const int nt0 = (job & 31) * 16;
            if (nt0 < cols) {
                const int c = nt0 + nn;
                const bool valid = (c < cols);
                const int cl = valid ? c : (cols - 1);
                const int a = lst1[cl >> 1];
                const int l = cl & 1;
                const int rp = (g2s[a] * 128 + sx2[a]) * 2 + l;

                const unsigned short* hg = h1 + (size_t)g * BN * DN
                                              + (size_t)(wave * 16 + nn) * DN + quad * 8;
                const unsigned short* wp = Wcs + (size_t)rp * DN + quad * 8;

                floatx4 acc = {0, 0, 0, 0};
                #pragma unroll
                for (int kk = 0; kk < KI; ++kk) {
                    short8 af = *(const short8*)(hg + kk * 32);
                    short8 bf = *(const short8*)(wp + kk * 32);
                    acc = __builtin_amdgcn_mfma_f32_16x16x32_bf16(af, bf, acc, 0, 0, 0);
                }
                if (valid) {
                    const float bv = bc[a * 2 + l];
                    #pragma unroll
                    for (int r = 0; r < 4; ++r)
                        out[(size_t)(wave * 16 + quad * 4 + r) * (AN * LN) + a * 2 + l] =
                            acc[r] + bv;
                }
            }
            __syncthreads();   // LDS arrays reused by next job
        }
    }
}

extern "C" void kernel_launch(void* const* d_in, const int* in_sizes, int n_in,
                              void* d_out, int out_size, void* d_ws, size_t ws_size,
                              hipStream_t stream) {
    const float* pooled = (const float*)d_in[0];
    const float* W1     = (const float*)d_in[1];
    const float* b1     = (const float*)d_in[2];
    const float* W2     = (const float*)d_in[3];
    const float* b2     = (const float*)d_in[4];
    const float* Wh     = (const float*)d_in[5];
    const float* bh     = (const float*)d_in[6];
    const int*   g1i    = (const int*)d_in[7];
    const int*   g2i    = (const int*)d_in[8];
    float* out = (float*)d_out;

    // Workspace carve (16B multiples): flags + bc + h1 + Wcs ~= 3.5 MB.
    // Flags need no zeroing: harness re-poisons ws each iteration; MAGIC is
    // non-byte-repeating so a memset-style poison can't forge it, and a stale
    // MAGIC would anyway expose identical bytes (producers are deterministic).
    char* ws = (char*)d_ws;
    int*   flags = (int*)ws;                          ws += 256 * 4;
    float* bc    = (float*)ws;                        ws += 512 * 4;
    unsigned short* h1  = (unsigned short*)ws;        ws += (size_t)G1N * BN * DN * 2;
    unsigned short* Wcs = (unsigned short*)ws;

    k_all<<<dim3(256), dim3(256), 0, stream>>>(pooled, W1, b1, W2, b2, Wh, bh,
                                               g1i, g2i, h1, Wcs, bc, flags, out);
}

// Round 7
// 131.229 us; speedup vs baseline: 1.0582x; 1.0582x over previous
//
#include <hip/hip_runtime.h>

#define AN 256
#define BN 64
#define DN 768
#define LN 2
#define G1N 4
#define G2N 8
#define KI (DN / 32)   // 24 k-iterations of 32
#define PAD 776        // Whs row stride: 768+8 bf16 -> 2-way bank alias = free

typedef __attribute__((ext_vector_type(8))) short short8;   // 8 bf16
typedef __attribute__((ext_vector_type(4))) short bf16x4;   // 4 bf16
typedef __attribute__((ext_vector_type(4))) float floatx4;  // MFMA acc

static __device__ __forceinline__ unsigned short f2bf(float f) {
    union { float f; unsigned int u; } v; v.f = f;
    unsigned int r = v.u + 0x7FFF + ((v.u >> 16) & 1);  // RNE
    return (unsigned short)(r >> 16);
}
static __device__ __forceinline__ unsigned int pack2(float a, float b) {
    return (unsigned int)f2bf(a) | ((unsigned int)f2bf(b) << 16);
}

// ---------------------------------------------------------------------------
// k_main: 296 blocks x 256, static LDS 26.9 KB (all blocks co-resident).
//   bx <  192: h1 role, (g = bx/48, 16-col tile ct = bx%48).
//              R6 diagnosis: old 48-block strided W1 gather was the ~35 us
//              latency-bound pole (436 GB/s, 4 waves/CU). Now: 192 blocks,
//              W1 chunk loaded COALESCED (float2, 64B/row) into a 4.4 KB
//              double-buffered LDS tile, transposed on LDS read. A-fragments
//              converted from fp32 pooled in-register (L2-hot).
//   192..287 : Wc role (verbatim R5 body; reads W2 once into regs).
//   288..295 : bc role (verbatim R5 body).
// ---------------------------------------------------------------------------
__global__ __launch_bounds__(256) void k_main(
    const float* __restrict__ pooled, const float* __restrict__ W1,
    const float* __restrict__ b1, const float* __restrict__ W2,
    const float* __restrict__ b2, const float* __restrict__ Wh,
    const float* __restrict__ bh, const int* __restrict__ g2i,
    unsigned short* __restrict__ h1, unsigned short* __restrict__ Wcs,
    float* __restrict__ bc)
{
    __shared__ __align__(16) unsigned char smem[26880];   // union of roles
    const int tid = threadIdx.x, bx = blockIdx.x;
    const int lane = tid & 63, wave = tid >> 6;
    const int nn = lane & 15, quad = lane >> 4;

    if (bx < 192) {
        // ---------------- h1 role ----------------
        // ldsW[2][32][17] fp32: chunk = W1[g][kk*32 .. +32][e0 .. e0+16]
        float* ldsW = (float*)smem;
        const int g = bx / 48, e0 = (bx % 48) * 16;
        const float* src = W1 + (size_t)g * DN * DN + e0;
        const int r = tid >> 3, c2 = (tid & 7) * 2;   // 32 rows x 8 thr x float2

        {   // preload chunk 0
            float2 v = *(const float2*)(src + (size_t)r * DN + c2);
            float* d = ldsW + r * 17 + c2;
            d[0] = v.x; d[1] = v.y;
        }
        __syncthreads();

        const int mt = wave;                          // each wave owns 16 rows
        const float* Ap = pooled + (size_t)(mt * 16 + nn) * DN + quad * 8;
        floatx4 acc = {0, 0, 0, 0};
        for (int kk = 0; kk < KI; ++kk) {
            const int cur = kk & 1;
            // issue next chunk's global load early (T14: hide under compute)
            float2 vnext;
            if (kk + 1 < KI)
                vnext = *(const float2*)(src + (size_t)((kk + 1) * 32 + r) * DN + c2);

            // B-fragment: transposed LDS read (exact fp32 -> same f2bf bits)
            const float* wb = ldsW + cur * 544 + quad * 8 * 17 + nn;
            short8 bf;
            #pragma unroll
            for (int j = 0; j < 8; ++j)
                bf[j] = (short)f2bf(wb[j * 17]);

            // A-fragment: pooled fp32 -> bf16 in-register
            float4 a0 = *(const float4*)(Ap + kk * 32);
            float4 a1 = *(const float4*)(Ap + kk * 32 + 4);
            short8 af;
            af[0] = (short)f2bf(a0.x); af[1] = (short)f2bf(a0.y);
            af[2] = (short)f2bf(a0.z); af[3] = (short)f2bf(a0.w);
            af[4] = (short)f2bf(a1.x); af[5] = (short)f2bf(a1.y);
            af[6] = (short)f2bf(a1.z); af[7] = (short)f2bf(a1.w);

            acc = __builtin_amdgcn_mfma_f32_16x16x32_bf16(af, bf, acc, 0, 0, 0);

            // write-late: land next chunk, then barrier for reuse
            if (kk + 1 < KI) {
                float* d = ldsW + (cur ^ 1) * 544 + r * 17 + c2;
                d[0] = vnext.x; d[1] = vnext.y;
            }
            __syncthreads();
        }

        const int e = e0 + nn;
        const float bv = b1[g * DN + e];
        #pragma unroll
        for (int rr = 0; rr < 4; ++rr)
            h1[(size_t)g * BN * DN + (size_t)(mt * 16 + quad * 4 + rr) * DN + e] =
                f2bf(acc[rr] + bv);
    } else if (bx < 288) {
        // ---------------- Wc role (verbatim R5) ----------------
        int* g2s  = (int*)smem;                                  // [256]
        int* lst2 = (int*)(smem + 1024);                         // [256]
        unsigned short* Whs = (unsigned short*)(smem + 2048);    // [16][PAD] bf16

        const int j = bx - 192, g = j / 12, mbase = (j % 12) * 64;

        const int m_row = mbase + wave * 16 + nn;
        const float* ap = W2 + ((size_t)g * DN + m_row) * DN + quad * 8;
        short8 Areg[KI];
        #pragma unroll
        for (int kk = 0; kk < KI; ++kk) {
            float4 a0 = *(const float4*)(ap + kk * 32);
            float4 a1 = *(const float4*)(ap + kk * 32 + 4);
            short8 af;
            af[0] = (short)f2bf(a0.x); af[1] = (short)f2bf(a0.y);
            af[2] = (short)f2bf(a0.z); af[3] = (short)f2bf(a0.w);
            af[4] = (short)f2bf(a1.x); af[5] = (short)f2bf(a1.y);
            af[6] = (short)f2bf(a1.z); af[7] = (short)f2bf(a1.w);
            Areg[kk] = af;
        }

        g2s[tid] = g2i[tid];
        __syncthreads();
        const int my = g2s[tid];
        int rk = 0;
        for (int a2 = 0; a2 < tid; ++a2) rk += (g2s[a2] == my);
        if (my == g) lst2[rk] = tid;
        int n2g = 0;
        for (int a2 = 0; a2 < AN; ++a2) n2g += (g2s[a2] == g);
        __syncthreads();
        const int cols = 2 * n2g;

        const int al = tid >> 5, t32 = tid & 31;
        for (int c0 = 0; c0 < cols; c0 += 16) {
            const int sidx = (c0 >> 1) + al;
            if (sidx < n2g) {
                const int a = lst2[sidx];
                const float4* wa4 = (const float4*)(Wh + (size_t)a * (DN * LN));
                #pragma unroll
                for (int i = 0; i < 12; ++i) {
                    const int f4 = i * 32 + t32;          // 0..383
                    float4 v = wa4[f4];
                    const int e2 = f4 * 2;
                    *(unsigned int*)(Whs + (2 * al)     * PAD + e2) = pack2(v.x, v.z);
                    *(unsigned int*)(Whs + (2 * al + 1) * PAD + e2) = pack2(v.y, v.w);
                }
            }
            __syncthreads();
            const unsigned short* Brow = Whs + nn * PAD + quad * 8;
            floatx4 acc = {0, 0, 0, 0};
            #pragma unroll
            for (int kk = 0; kk < KI; ++kk) {
                short8 bf = *(const short8*)(Brow + kk * 32);
                acc = __builtin_amdgcn_mfma_f32_16x16x32_bf16(Areg[kk], bf, acc, 0, 0, 0);
            }
            const int c = c0 + nn;
            if (c < cols) {
                const int dbase = mbase + wave * 16 + quad * 4;
                bf16x4 v;
                #pragma unroll
                for (int rr = 0; rr < 4; ++rr) v[rr] = (short)f2bf(acc[rr]);
                *(bf16x4*)(Wcs + (size_t)(g * 256 + c) * DN + dbase) = v;
            }
            __syncthreads();
        }
    } else {
        // ---------------- bc role (verbatim R5) ----------------
        const int jb = bx - 288;
        const int aa = tid >> 3, jj = tid & 7;
        const int a = jb * 32 + aa;
        const int gv2 = g2i[a];
        const float* whp = Wh + (size_t)a * (DN * LN);
        const float* b2p = b2 + gv2 * DN;
        float acc0 = 0.f, acc1 = 0.f;
        #pragma unroll 4
        for (int i = 0; i < 48; ++i) {
            int e = jj * 96 + i * 2;
            float4 w4 = *(const float4*)(whp + e * 2);
            float2 bv = *(const float2*)(b2p + e);
            acc0 += bv.x * w4.x + bv.y * w4.z;
            acc1 += bv.x * w4.y + bv.y * w4.w;
        }
        #pragma unroll
        for (int off = 4; off; off >>= 1) {
            acc0 += __shfl_down(acc0, off, 64);
            acc1 += __shfl_down(acc1, off, 64);
        }
        if (jj == 0) {
            bc[a * 2 + 0] = acc0 + bh[a * 2 + 0];
            bc[a * 2 + 1] = acc1 + bh[a * 2 + 1];
        }
    }
}

// ---------------------------------------------------------------------------
// k_out: grid (32, 4) x 256 (verbatim R5, proven). Index lists via in-block
// rank-scan; out[b,a,l] = h1[g1(a)][b,:] . Wcs[..] + bc.
// ---------------------------------------------------------------------------
__global__ __launch_bounds__(256) void k_out(
    const unsigned short* __restrict__ h1, const unsigned short* __restrict__ Wcs,
    const float* __restrict__ bc, const int* __restrict__ g1i,
    const int* __restrict__ g2i, float* __restrict__ out)
{
    __shared__ int g1s[AN], g2s[AN], lst1[AN], sx2[AN];
    const int g = blockIdx.y;
    const int tid = threadIdx.x;
    g1s[tid] = g1i[tid];
    g2s[tid] = g2i[tid];
    __syncthreads();
    const int m1 = g1s[tid], m2 = g2s[tid];
    int r1 = 0, r2 = 0;
    for (int a2 = 0; a2 < tid; ++a2) {
        r1 += (g1s[a2] == m1);
        r2 += (g2s[a2] == m2);
    }
    sx2[tid] = r2;
    if (m1 == g) lst1[r1] = tid;
    int n1g = 0;
    for (int a2 = 0; a2 < AN; ++a2) n1g += (g1s[a2] == g);
    __syncthreads();

    const int cols = 2 * n1g;
    const int nt0 = blockIdx.x * 16;
    if (nt0 >= cols) return;

    const int lane = tid & 63, wave = tid >> 6;
    const int nn = lane & 15, quad = lane >> 4;

    const int c = nt0 + nn;
    const bool valid = (c < cols);
    const int cl = valid ? c : (cols - 1);
    const int a = lst1[cl >> 1];
    const int l = cl & 1;
    const int rp = (g2s[a] * 128 + sx2[a]) * 2 + l;

    const unsigned short* hg = h1 + (size_t)g * BN * DN + (size_t)(wave * 16 + nn) * DN + quad * 8;
    const unsigned short* wp = Wcs + (size_t)rp * DN + quad * 8;

    floatx4 acc = {0, 0, 0, 0};
    #pragma unroll
    for (int kk = 0; kk < KI; ++kk) {
        short8 af = *(const short8*)(hg + kk * 32);
        short8 bf = *(const short8*)(wp + kk * 32);
        acc = __builtin_amdgcn_mfma_f32_16x16x32_bf16(af, bf, acc, 0, 0, 0);
    }
    if (valid) {
        const float bv = bc[a * 2 + l];
        #pragma unroll
        for (int r = 0; r < 4; ++r)
            out[(size_t)(wave * 16 + quad * 4 + r) * (AN * LN) + a * 2 + l] = acc[r] + bv;
    }
}

extern "C" void kernel_launch(void* const* d_in, const int* in_sizes, int n_in,
                              void* d_out, int out_size, void* d_ws, size_t ws_size,
                              hipStream_t stream) {
    const float* pooled = (const float*)d_in[0];
    const float* W1     = (const float*)d_in[1];
    const float* b1     = (const float*)d_in[2];
    const float* W2     = (const float*)d_in[3];
    const float* b2     = (const float*)d_in[4];
    const float* Wh     = (const float*)d_in[5];
    const float* bh     = (const float*)d_in[6];
    const int*   g1i    = (const int*)d_in[7];
    const int*   g2i    = (const int*)d_in[8];
    float* out = (float*)d_out;

    // Workspace carve (16B multiples): bc + h1 + Wcs ~= 3.5 MB
    char* ws = (char*)d_ws;
    float* bc = (float*)ws;                           ws += 512 * 4;
    unsigned short* h1  = (unsigned short*)ws;        ws += (size_t)G1N * BN * DN * 2;
    unsigned short* Wcs = (unsigned short*)ws;

    dim3 blk(256);
    k_main<<<dim3(296),   blk, 0, stream>>>(pooled, W1, b1, W2, b2, Wh, bh, g2i,
                                            h1, Wcs, bc);
    k_out <<<dim3(32, 4), blk, 0, stream>>>(h1, Wcs, bc, g1i, g2i, out);
}

// Round 9
// 117.835 us; speedup vs baseline: 1.1785x; 1.1137x over previous
//
#include <hip/hip_runtime.h>

#define AN 256
#define BN 64
#define DN 768
#define LN 2
#define G1N 4
#define G2N 8
#define KI (DN / 32)   // 24 k-iterations of 32
#define PAD 776        // row stride in bf16: 768+8 -> bank-alias 2-way = free

typedef __attribute__((ext_vector_type(8))) short short8;   // 8 bf16
typedef __attribute__((ext_vector_type(4))) short bf16x4;   // 4 bf16
typedef __attribute__((ext_vector_type(4))) float floatx4;  // MFMA acc

static __device__ __forceinline__ unsigned short f2bf(float f) {
    union { float f; unsigned int u; } v; v.f = f;
    unsigned int r = v.u + 0x7FFF + ((v.u >> 16) & 1);  // RNE
    return (unsigned short)(r >> 16);
}
static __device__ __forceinline__ unsigned int pack2(float a, float b) {
    return (unsigned int)f2bf(a) | ((unsigned int)f2bf(b) << 16);
}

// ---------------------------------------------------------------------------
// k_main: 200 blocks x 256, static LDS 49.7 KB; grid < 256 -> 1 block/CU,
// single dispatch wave, all roles co-resident.
//   bx <  96 : h1 role, (g = bx/24, 32-col tile). R7 post-mortem: per-k-step
//              barriers exposed full HBM latency at 1 wave/SIMD. Now: stage
//              the whole W1 column slab ONCE (24 independent coalesced
//              float4 loads/thread, full 128B lines), ONE barrier, then
//              barrier-free MFMA loop (compiler pipelines A-loads + LDS
//              reads across all 24 k-steps).
//   96..191  : Wc role (verbatim R5/R7 body).
//   192..199 : bc role (verbatim).
// ---------------------------------------------------------------------------
__global__ __launch_bounds__(256) void k_main(
    const float* __restrict__ pooled, const float* __restrict__ W1,
    const float* __restrict__ b1, const float* __restrict__ W2,
    const float* __restrict__ b2, const float* __restrict__ Wh,
    const float* __restrict__ bh, const int* __restrict__ g2i,
    unsigned short* __restrict__ h1, unsigned short* __restrict__ Wcs,
    float* __restrict__ bc)
{
    __shared__ __align__(16) unsigned char smem[49664];   // union of roles
    const int tid = threadIdx.x, bx = blockIdx.x;
    const int lane = tid & 63, wave = tid >> 6;
    const int nn = lane & 15, quad = lane >> 4;

    if (bx < 96) {
        // ---------------- h1 role ----------------
        unsigned short* Wt = (unsigned short*)smem;          // [32][PAD] bf16, transposed
        const int g = bx / 24, e0 = (bx % 24) * 32;
        const float* src = W1 + (size_t)g * DN * DN + e0;
        const int dr = tid >> 3, q8 = tid & 7;               // 32 rows x 8thr x float4

        // stage whole slab: W1[g][d][e0+c] -> Wt[c][d]; 24 independent rounds
        #pragma unroll
        for (int round = 0; round < 24; ++round) {
            const int d = round * 32 + dr;
            float4 v = *(const float4*)(src + (size_t)d * DN + q8 * 4);
            Wt[(q8 * 4 + 0) * PAD + d] = f2bf(v.x);
            Wt[(q8 * 4 + 1) * PAD + d] = f2bf(v.y);
            Wt[(q8 * 4 + 2) * PAD + d] = f2bf(v.z);
            Wt[(q8 * 4 + 3) * PAD + d] = f2bf(v.w);
        }
        __syncthreads();

        // barrier-free compute: wave owns 16 b-rows (mt), 2 col-halves
        const int mt = wave;
        const float* Ap = pooled + (size_t)(mt * 16 + nn) * DN + quad * 8;
        floatx4 acc0 = {0, 0, 0, 0}, acc1 = {0, 0, 0, 0};
        #pragma unroll
        for (int kk = 0; kk < KI; ++kk) {
            float4 a0 = *(const float4*)(Ap + kk * 32);
            float4 a1 = *(const float4*)(Ap + kk * 32 + 4);
            short8 af;
            af[0] = (short)f2bf(a0.x); af[1] = (short)f2bf(a0.y);
            af[2] = (short)f2bf(a0.z); af[3] = (short)f2bf(a0.w);
            af[4] = (short)f2bf(a1.x); af[5] = (short)f2bf(a1.y);
            af[6] = (short)f2bf(a1.z); af[7] = (short)f2bf(a1.w);
            short8 bf0 = *(const short8*)(Wt + (size_t)nn * PAD + kk * 32 + quad * 8);
            short8 bf1 = *(const short8*)(Wt + (size_t)(16 + nn) * PAD + kk * 32 + quad * 8);
            acc0 = __builtin_amdgcn_mfma_f32_16x16x32_bf16(af, bf0, acc0, 0, 0, 0);
            acc1 = __builtin_amdgcn_mfma_f32_16x16x32_bf16(af, bf1, acc1, 0, 0, 0);
        }

        const float bv0 = b1[g * DN + e0 + nn];
        const float bv1 = b1[g * DN + e0 + 16 + nn];
        unsigned short* hrow = h1 + (size_t)g * BN * DN;
        #pragma unroll
        for (int rr = 0; rr < 4; ++rr) {
            const size_t ro = (size_t)(mt * 16 + quad * 4 + rr) * DN;
            hrow[ro + e0 + nn]      = f2bf(acc0[rr] + bv0);
            hrow[ro + e0 + 16 + nn] = f2bf(acc1[rr] + bv1);
        }
    } else if (bx < 192) {
        // ---------------- Wc role (verbatim) ----------------
        int* g2s  = (int*)smem;                                  // [256]
        int* lst2 = (int*)(smem + 1024);                         // [256]
        unsigned short* Whs = (unsigned short*)(smem + 2048);    // [16][PAD] bf16

        const int j = bx - 96, g = j / 12, mbase = (j % 12) * 64;

        const int m_row = mbase + wave * 16 + nn;
        const float* ap = W2 + ((size_t)g * DN + m_row) * DN + quad * 8;
        short8 Areg[KI];
        #pragma unroll
        for (int kk = 0; kk < KI; ++kk) {
            float4 a0 = *(const float4*)(ap + kk * 32);
            float4 a1 = *(const float4*)(ap + kk * 32 + 4);
            short8 af;
            af[0] = (short)f2bf(a0.x); af[1] = (short)f2bf(a0.y);
            af[2] = (short)f2bf(a0.z); af[3] = (short)f2bf(a0.w);
            af[4] = (short)f2bf(a1.x); af[5] = (short)f2bf(a1.y);
            af[6] = (short)f2bf(a1.z); af[7] = (short)f2bf(a1.w);
            Areg[kk] = af;
        }

        g2s[tid] = g2i[tid];
        __syncthreads();
        const int my = g2s[tid];
        int rk = 0;
        for (int a2 = 0; a2 < tid; ++a2) rk += (g2s[a2] == my);
        if (my == g) lst2[rk] = tid;
        int n2g = 0;
        for (int a2 = 0; a2 < AN; ++a2) n2g += (g2s[a2] == g);
        __syncthreads();
        const int cols = 2 * n2g;

        const int al = tid >> 5, t32 = tid & 31;
        for (int c0 = 0; c0 < cols; c0 += 16) {
            const int sidx = (c0 >> 1) + al;
            if (sidx < n2g) {
                const int a = lst2[sidx];
                const float4* wa4 = (const float4*)(Wh + (size_t)a * (DN * LN));
                #pragma unroll
                for (int i = 0; i < 12; ++i) {
                    const int f4 = i * 32 + t32;          // 0..383
                    float4 v = wa4[f4];
                    const int e2 = f4 * 2;
                    *(unsigned int*)(Whs + (2 * al)     * PAD + e2) = pack2(v.x, v.z);
                    *(unsigned int*)(Whs + (2 * al + 1) * PAD + e2) = pack2(v.y, v.w);
                }
            }
            __syncthreads();
            const unsigned short* Brow = Whs + nn * PAD + quad * 8;
            floatx4 acc = {0, 0, 0, 0};
            #pragma unroll
            for (int kk = 0; kk < KI; ++kk) {
                short8 bf = *(const short8*)(Brow + kk * 32);
                acc = __builtin_amdgcn_mfma_f32_16x16x32_bf16(Areg[kk], bf, acc, 0, 0, 0);
            }
            const int c = c0 + nn;
            if (c < cols) {
                const int dbase = mbase + wave * 16 + quad * 4;
                bf16x4 v;
                #pragma unroll
                for (int rr = 0; rr < 4; ++rr) v[rr] = (short)f2bf(acc[rr]);
                *(bf16x4*)(Wcs + (size_t)(g * 256 + c) * DN + dbase) = v;
            }
            __syncthreads();
        }
    } else {
        // ---------------- bc role (verbatim) ----------------
        const int jb = bx - 192;
        const int aa = tid >> 3, jj = tid & 7;
        const int a = jb * 32 + aa;
        const int gv2 = g2i[a];
        const float* whp = Wh + (size_t)a * (DN * LN);
        const float* b2p = b2 + gv2 * DN;
        float acc0 = 0.f, acc1 = 0.f;
        #pragma unroll 4
        for (int i = 0; i < 48; ++i) {
            int e = jj * 96 + i * 2;
            float4 w4 = *(const float4*)(whp + e * 2);
            float2 bv = *(const float2*)(b2p + e);
            acc0 += bv.x * w4.x + bv.y * w4.z;
            acc1 += bv.x * w4.y + bv.y * w4.w;
        }
        #pragma unroll
        for (int off = 4; off; off >>= 1) {
            acc0 += __shfl_down(acc0, off, 64);
            acc1 += __shfl_down(acc1, off, 64);
        }
        if (jj == 0) {
            bc[a * 2 + 0] = acc0 + bh[a * 2 + 0];
            bc[a * 2 + 1] = acc1 + bh[a * 2 + 1];
        }
    }
}

// ---------------------------------------------------------------------------
// k_out: grid (32, 4) x 256 (verbatim, proven). Index lists via in-block
// rank-scan; out[b,a,l] = h1[g1(a)][b,:] . Wcs[..] + bc.
// ---------------------------------------------------------------------------
__global__ __launch_bounds__(256) void k_out(
    const unsigned short* __restrict__ h1, const unsigned short* __restrict__ Wcs,
    const float* __restrict__ bc, const int* __restrict__ g1i,
    const int* __restrict__ g2i, float* __restrict__ out)
{
    __shared__ int g1s[AN], g2s[AN], lst1[AN], sx2[AN];
    const int g = blockIdx.y;
    const int tid = threadIdx.x;
    g1s[tid] = g1i[tid];
    g2s[tid] = g2i[tid];
    __syncthreads();
    const int m1 = g1s[tid], m2 = g2s[tid];
    int r1 = 0, r2 = 0;
    for (int a2 = 0; a2 < tid; ++a2) {
        r1 += (g1s[a2] == m1);
        r2 += (g2s[a2] == m2);
    }
    sx2[tid] = r2;
    if (m1 == g) lst1[r1] = tid;
    int n1g = 0;
    for (int a2 = 0; a2 < AN; ++a2) n1g += (g1s[a2] == g);
    __syncthreads();

    const int cols = 2 * n1g;
    const int nt0 = blockIdx.x * 16;
    if (nt0 >= cols) return;

    const int lane = tid & 63, wave = tid >> 6;
    const int nn = lane & 15, quad = lane >> 4;

    const int c = nt0 + nn;
    const bool valid = (c < cols);
    const int cl = valid ? c : (cols - 1);
    const int a = lst1[cl >> 1];
    const int l = cl & 1;
    const int rp = (g2s[a] * 128 + sx2[a]) * 2 + l;

    const unsigned short* hg = h1 + (size_t)g * BN * DN + (size_t)(wave * 16 + nn) * DN + quad * 8;
    const unsigned short* wp = Wcs + (size_t)rp * DN + quad * 8;

    floatx4 acc = {0, 0, 0, 0};
    #pragma unroll
    for (int kk = 0; kk < KI; ++kk) {
        short8 af = *(const short8*)(hg + kk * 32);
        short8 bf = *(const short8*)(wp + kk * 32);
        acc = __builtin_amdgcn_mfma_f32_16x16x32_bf16(af, bf, acc, 0, 0, 0);
    }
    if (valid) {
        const float bv = bc[a * 2 + l];
        #pragma unroll
        for (int r = 0; r < 4; ++r)
            out[(size_t)(wave * 16 + quad * 4 + r) * (AN * LN) + a * 2 + l] = acc[r] + bv;
    }
}

extern "C" void kernel_launch(void* const* d_in, const int* in_sizes, int n_in,
                              void* d_out, int out_size, void* d_ws, size_t ws_size,
                              hipStream_t stream) {
    const float* pooled = (const float*)d_in[0];
    const float* W1     = (const float*)d_in[1];
    const float* b1     = (const float*)d_in[2];
    const float* W2     = (const float*)d_in[3];
    const float* b2     = (const float*)d_in[4];
    const float* Wh     = (const float*)d_in[5];
    const float* bh     = (const float*)d_in[6];
    const int*   g1i    = (const int*)d_in[7];
    const int*   g2i    = (const int*)d_in[8];
    float* out = (float*)d_out;

    // Workspace carve (16B multiples): bc + h1 + Wcs ~= 3.5 MB
    char* ws = (char*)d_ws;
    float* bc = (float*)ws;                           ws += 512 * 4;
    unsigned short* h1  = (unsigned short*)ws;        ws += (size_t)G1N * BN * DN * 2;
    unsigned short* Wcs = (unsigned short*)ws;

    dim3 blk(256);
    k_main<<<dim3(200),   blk, 0, stream>>>(pooled, W1, b1, W2, b2, Wh, bh, g2i,
                                            h1, Wcs, bc);
    k_out <<<dim3(32, 4), blk, 0, stream>>>(h1, Wcs, bc, g1i, g2i, out);
}

// Round 10
// 117.774 us; speedup vs baseline: 1.1791x; 1.0005x over previous
//
#include <hip/hip_runtime.h>

#define AN 256
#define BN 64
#define DN 768
#define LN 2
#define G1N 4
#define G2N 8
#define KI (DN / 32)   // 24 k-iterations of 32
#define PAD 776        // row stride in bf16: 768+8 -> bank-alias 2-way = free

typedef __attribute__((ext_vector_type(8))) short short8;   // 8 bf16
typedef __attribute__((ext_vector_type(4))) short bf16x4;   // 4 bf16
typedef __attribute__((ext_vector_type(4))) float floatx4;  // MFMA acc

static __device__ __forceinline__ unsigned short f2bf(float f) {
    union { float f; unsigned int u; } v; v.f = f;
    unsigned int r = v.u + 0x7FFF + ((v.u >> 16) & 1);  // RNE
    return (unsigned short)(r >> 16);
}
static __device__ __forceinline__ unsigned int pack2(float a, float b) {
    return (unsigned int)f2bf(a) | ((unsigned int)f2bf(b) << 16);
}

// ---------------------------------------------------------------------------
// k_main: 200 blocks x 256, static LDS 151 KB; 1 block/CU, single dispatch
// wave, all roles co-resident.
//   bx <  96 : h1 role (verbatim R9: slab-stage once, barrier-free MFMA).
//   96..191  : Wc role, REWORKED (R9 flat vs R5 -> h1 wasn't the pole; Wc is
//              the remaining candidate): (a) W2 slab now staged COALESCED
//              (48 independent float4/thread) into LDS bf16 [64][776], one
//              barrier, Areg read as contiguous short8 — replaces the
//              48 strided-3KB loads/thread; (b) Whs double-buffered, one
//              barrier per tile, staging overlapped with MFMA issue.
//   192..199 : bc role (verbatim).
// ---------------------------------------------------------------------------
__global__ __launch_bounds__(256) void k_main(
    const float* __restrict__ pooled, const float* __restrict__ W1,
    const float* __restrict__ b1, const float* __restrict__ W2,
    const float* __restrict__ b2, const float* __restrict__ Wh,
    const float* __restrict__ bh, const int* __restrict__ g2i,
    unsigned short* __restrict__ h1, unsigned short* __restrict__ Wcs,
    float* __restrict__ bc)
{
    // layout (Wc role): W2s [64][PAD] bf16 = 99328 B
    //                   Whs [2][16][PAD] bf16 = 49664 B   @ +99328
    //                   g2s [256] int = 1024 B            @ +148992
    //                   lst2[256] int = 1024 B            @ +150016
    __shared__ __align__(16) unsigned char smem[151040];
    const int tid = threadIdx.x, bx = blockIdx.x;
    const int lane = tid & 63, wave = tid >> 6;
    const int nn = lane & 15, quad = lane >> 4;

    if (bx < 96) {
        // ---------------- h1 role (verbatim R9) ----------------
        unsigned short* Wt = (unsigned short*)smem;          // [32][PAD] bf16
        const int g = bx / 24, e0 = (bx % 24) * 32;
        const float* src = W1 + (size_t)g * DN * DN + e0;
        const int dr = tid >> 3, q8 = tid & 7;

        #pragma unroll
        for (int round = 0; round < 24; ++round) {
            const int d = round * 32 + dr;
            float4 v = *(const float4*)(src + (size_t)d * DN + q8 * 4);
            Wt[(q8 * 4 + 0) * PAD + d] = f2bf(v.x);
            Wt[(q8 * 4 + 1) * PAD + d] = f2bf(v.y);
            Wt[(q8 * 4 + 2) * PAD + d] = f2bf(v.z);
            Wt[(q8 * 4 + 3) * PAD + d] = f2bf(v.w);
        }
        __syncthreads();

        const int mt = wave;
        const float* Ap = pooled + (size_t)(mt * 16 + nn) * DN + quad * 8;
        floatx4 acc0 = {0, 0, 0, 0}, acc1 = {0, 0, 0, 0};
        #pragma unroll
        for (int kk = 0; kk < KI; ++kk) {
            float4 a0 = *(const float4*)(Ap + kk * 32);
            float4 a1 = *(const float4*)(Ap + kk * 32 + 4);
            short8 af;
            af[0] = (short)f2bf(a0.x); af[1] = (short)f2bf(a0.y);
            af[2] = (short)f2bf(a0.z); af[3] = (short)f2bf(a0.w);
            af[4] = (short)f2bf(a1.x); af[5] = (short)f2bf(a1.y);
            af[6] = (short)f2bf(a1.z); af[7] = (short)f2bf(a1.w);
            short8 bf0 = *(const short8*)(Wt + (size_t)nn * PAD + kk * 32 + quad * 8);
            short8 bf1 = *(const short8*)(Wt + (size_t)(16 + nn) * PAD + kk * 32 + quad * 8);
            acc0 = __builtin_amdgcn_mfma_f32_16x16x32_bf16(af, bf0, acc0, 0, 0, 0);
            acc1 = __builtin_amdgcn_mfma_f32_16x16x32_bf16(af, bf1, acc1, 0, 0, 0);
        }

        const float bv0 = b1[g * DN + e0 + nn];
        const float bv1 = b1[g * DN + e0 + 16 + nn];
        unsigned short* hrow = h1 + (size_t)g * BN * DN;
        #pragma unroll
        for (int rr = 0; rr < 4; ++rr) {
            const size_t ro = (size_t)(mt * 16 + quad * 4 + rr) * DN;
            hrow[ro + e0 + nn]      = f2bf(acc0[rr] + bv0);
            hrow[ro + e0 + 16 + nn] = f2bf(acc1[rr] + bv1);
        }
    } else if (bx < 192) {
        // ---------------- Wc role (reworked) ----------------
        unsigned short* W2s = (unsigned short*)smem;             // [64][PAD]
        unsigned short* Whs = (unsigned short*)(smem + 99328);   // [2][16][PAD]
        int* g2s  = (int*)(smem + 148992);                       // [256]
        int* lst2 = (int*)(smem + 150016);                       // [256]

        const int j = bx - 96, g = j / 12, mbase = (j % 12) * 64;

        // (a) coalesced W2 slab -> LDS bf16 (48 independent float4/thread)
        g2s[tid] = g2i[tid];
        {
            const float* sl = W2 + ((size_t)g * DN + mbase) * DN;   // 64 x 768
            #pragma unroll
            for (int i = 0; i < 48; ++i) {
                const int idx = i * 256 + tid;                      // 12288 float4
                const int r = idx / 192, c4 = idx % 192;
                float4 v = *(const float4*)(sl + (size_t)r * DN + c4 * 4);
                bf16x4 b;
                b[0] = (short)f2bf(v.x); b[1] = (short)f2bf(v.y);
                b[2] = (short)f2bf(v.z); b[3] = (short)f2bf(v.w);
                *(bf16x4*)(W2s + (size_t)r * PAD + c4 * 4) = b;
            }
        }
        __syncthreads();

        // Areg from LDS (contiguous short8 reads) + rank-scan
        short8 Areg[KI];
        {
            const unsigned short* ar = W2s + (size_t)(wave * 16 + nn) * PAD + quad * 8;
            #pragma unroll
            for (int kk = 0; kk < KI; ++kk)
                Areg[kk] = *(const short8*)(ar + kk * 32);
        }
        const int my = g2s[tid];
        int rk = 0;
        for (int a2 = 0; a2 < tid; ++a2) rk += (g2s[a2] == my);
        if (my == g) lst2[rk] = tid;
        int n2g = 0;
        for (int a2 = 0; a2 < AN; ++a2) n2g += (g2s[a2] == g);
        __syncthreads();                    // lst2 ready
        const int cols = 2 * n2g;
        const int ntiles = (cols + 15) >> 4;

        // (b) Whs double-buffered; one barrier per tile
        const int al = tid >> 5, t32 = tid & 31;
        // prologue: stage tile 0 -> buf 0
        if (al < n2g) {
            const int a = lst2[al];
            const float4* wa4 = (const float4*)(Wh + (size_t)a * (DN * LN));
            #pragma unroll
            for (int i = 0; i < 12; ++i) {
                const int f4 = i * 32 + t32;
                float4 v = wa4[f4];
                const int e2 = f4 * 2;
                *(unsigned int*)(Whs + (size_t)(2 * al)     * PAD + e2) = pack2(v.x, v.z);
                *(unsigned int*)(Whs + (size_t)(2 * al + 1) * PAD + e2) = pack2(v.y, v.w);
            }
        }
        __syncthreads();

        for (int t = 0; t < ntiles; ++t) {
            const int cur = t & 1;
            const unsigned short* Brow = Whs + (size_t)(cur * 16 + nn) * PAD + quad * 8;
            floatx4 acc = {0, 0, 0, 0};
            #pragma unroll
            for (int kk = 0; kk < KI; ++kk) {
                short8 bf = *(const short8*)(Brow + kk * 32);
                acc = __builtin_amdgcn_mfma_f32_16x16x32_bf16(Areg[kk], bf, acc, 0, 0, 0);
            }
            // stage tile t+1 into the other buffer (overlaps MFMA execution)
            const int sidx = ((t + 1) << 3) + al;
            if (t + 1 < ntiles && sidx < n2g) {
                const int a = lst2[sidx];
                const float4* wa4 = (const float4*)(Wh + (size_t)a * (DN * LN));
                unsigned short* dst = Whs + (size_t)((cur ^ 1) * 16) * PAD;
                #pragma unroll
                for (int i = 0; i < 12; ++i) {
                    const int f4 = i * 32 + t32;
                    float4 v = wa4[f4];
                    const int e2 = f4 * 2;
                    *(unsigned int*)(dst + (size_t)(2 * al)     * PAD + e2) = pack2(v.x, v.z);
                    *(unsigned int*)(dst + (size_t)(2 * al + 1) * PAD + e2) = pack2(v.y, v.w);
                }
            }
            const int c = t * 16 + nn;
            if (c < cols) {
                const int dbase = mbase + wave * 16 + quad * 4;
                bf16x4 v;
                #pragma unroll
                for (int rr = 0; rr < 4; ++rr) v[rr] = (short)f2bf(acc[rr]);
                *(bf16x4*)(Wcs + (size_t)(g * 256 + c) * DN + dbase) = v;
            }
            __syncthreads();   // cur reads done + next buffer written
        }
    } else {
        // ---------------- bc role (verbatim) ----------------
        const int jb = bx - 192;
        const int aa = tid >> 3, jj = tid & 7;
        const int a = jb * 32 + aa;
        const int gv2 = g2i[a];
        const float* whp = Wh + (size_t)a * (DN * LN);
        const float* b2p = b2 + gv2 * DN;
        float acc0 = 0.f, acc1 = 0.f;
        #pragma unroll 4
        for (int i = 0; i < 48; ++i) {
            int e = jj * 96 + i * 2;
            float4 w4 = *(const float4*)(whp + e * 2);
            float2 bv = *(const float2*)(b2p + e);
            acc0 += bv.x * w4.x + bv.y * w4.z;
            acc1 += bv.x * w4.y + bv.y * w4.w;
        }
        #pragma unroll
        for (int off = 4; off; off >>= 1) {
            acc0 += __shfl_down(acc0, off, 64);
            acc1 += __shfl_down(acc1, off, 64);
        }
        if (jj == 0) {
            bc[a * 2 + 0] = acc0 + bh[a * 2 + 0];
            bc[a * 2 + 1] = acc1 + bh[a * 2 + 1];
        }
    }
}

// ---------------------------------------------------------------------------
// k_out: grid (32, 4) x 256 (verbatim, proven). Index lists via in-block
// rank-scan; out[b,a,l] = h1[g1(a)][b,:] . Wcs[..] + bc.
// ---------------------------------------------------------------------------
__global__ __launch_bounds__(256) void k_out(
    const unsigned short* __restrict__ h1, const unsigned short* __restrict__ Wcs,
    const float* __restrict__ bc, const int* __restrict__ g1i,
    const int* __restrict__ g2i, float* __restrict__ out)
{
    __shared__ int g1s[AN], g2s[AN], lst1[AN], sx2[AN];
    const int g = blockIdx.y;
    const int tid = threadIdx.x;
    g1s[tid] = g1i[tid];
    g2s[tid] = g2i[tid];
    __syncthreads();
    const int m1 = g1s[tid], m2 = g2s[tid];
    int r1 = 0, r2 = 0;
    for (int a2 = 0; a2 < tid; ++a2) {
        r1 += (g1s[a2] == m1);
        r2 += (g2s[a2] == m2);
    }
    sx2[tid] = r2;
    if (m1 == g) lst1[r1] = tid;
    int n1g = 0;
    for (int a2 = 0; a2 < AN; ++a2) n1g += (g1s[a2] == g);
    __syncthreads();

    const int cols = 2 * n1g;
    const int nt0 = blockIdx.x * 16;
    if (nt0 >= cols) return;

    const int lane = tid & 63, wave = tid >> 6;
    const int nn = lane & 15, quad = lane >> 4;

    const int c = nt0 + nn;
    const bool valid = (c < cols);
    const int cl = valid ? c : (cols - 1);
    const int a = lst1[cl >> 1];
    const int l = cl & 1;
    const int rp = (g2s[a] * 128 + sx2[a]) * 2 + l;

    const unsigned short* hg = h1 + (size_t)g * BN * DN + (size_t)(wave * 16 + nn) * DN + quad * 8;
    const unsigned short* wp = Wcs + (size_t)rp * DN + quad * 8;

    floatx4 acc = {0, 0, 0, 0};
    #pragma unroll
    for (int kk = 0; kk < KI; ++kk) {
        short8 af = *(const short8*)(hg + kk * 32);
        short8 bf = *(const short8*)(wp + kk * 32);
        acc = __builtin_amdgcn_mfma_f32_16x16x32_bf16(af, bf, acc, 0, 0, 0);
    }
    if (valid) {
        const float bv = bc[a * 2 + l];
        #pragma unroll
        for (int r = 0; r < 4; ++r)
            out[(size_t)(wave * 16 + quad * 4 + r) * (AN * LN) + a * 2 + l] = acc[r] + bv;
    }
}

extern "C" void kernel_launch(void* const* d_in, const int* in_sizes, int n_in,
                              void* d_out, int out_size, void* d_ws, size_t ws_size,
                              hipStream_t stream) {
    const float* pooled = (const float*)d_in[0];
    const float* W1     = (const float*)d_in[1];
    const float* b1     = (const float*)d_in[2];
    const float* W2     = (const float*)d_in[3];
    const float* b2     = (const float*)d_in[4];
    const float* Wh     = (const float*)d_in[5];
    const float* bh     = (const float*)d_in[6];
    const int*   g1i    = (const int*)d_in[7];
    const int*   g2i    = (const int*)d_in[8];
    float* out = (float*)d_out;

    // Workspace carve (16B multiples): bc + h1 + Wcs ~= 3.5 MB
    char* ws = (char*)d_ws;
    float* bc = (float*)ws;                           ws += 512 * 4;
    unsigned short* h1  = (unsigned short*)ws;        ws += (size_t)G1N * BN * DN * 2;
    unsigned short* Wcs = (unsigned short*)ws;

    dim3 blk(256);
    k_main<<<dim3(200),   blk, 0, stream>>>(pooled, W1, b1, W2, b2, Wh, bh, g2i,
                                            h1, Wcs, bc);
    k_out <<<dim3(32, 4), blk, 0, stream>>>(h1, Wcs, bc, g1i, g2i, out);
}